// Round 4
// baseline (234.929 us; speedup 1.0000x reference)
//
#include <hip/hip_runtime.h>

// RY(theta) single-qubit gate on batched state vector.
// state: [B=32, 2^20] fp32. Target qubit q (static=3) maps to flat-index
// bit (20-1-q) = 16, i.e. element stride 2^16. Butterfly per pair:
//   y0 = c*x0 - s*x1 ; y1 = s*x0 + c*x1 ; t=theta/2, c=cos t, s=sin t.
// Memory-bound: 256 MiB app traffic -> ~43 us floor at 6.3 TB/s.
//
// R6: de-confound R4's A/B. R4 flipped loads AND stores NT->plain together
// (-7 us). Store-NT is clearly right (output never re-read; plain stores
// write-allocate 128 MiB and evict input from LLC). Load-NT is suspect:
// the nt bit marks input lines low-retention, making them preferred
// eviction victims for the harness's 2x512 MiB poison fills -- consistent
// with R4's FETCH_SIZE=64 MiB (only half the input LLC-resident). This
// round: PLAIN loads (normal retention) + NT stores. Structure unchanged
// from R5 (persistent grid-stride, depth-1 pipeline, wave-dense 1 KiB
// VMEM instructions). Predict FETCH < 64 MiB, total -4..-8 us; if
// unchanged, the kernel slice is at its wall (rest is harness fills).

typedef float floatx4 __attribute__((ext_vector_type(4)));

__global__ __launch_bounds__(256) void ry_gate_kernel(
    const float* __restrict__ in,
    const float* __restrict__ theta,
    const int*   __restrict__ qubit,
    float*       __restrict__ out,
    unsigned int n_chunks)   // chunks of 512 lower + 512 upper floats
{
    const unsigned int n_act_waves = (gridDim.x * blockDim.x) >> 6;
    const unsigned int tid  = blockIdx.x * blockDim.x + threadIdx.x;
    const unsigned int lane = threadIdx.x & 63u;
    unsigned int chunk = tid >> 6;
    if (chunk >= n_chunks) return;

    // n = 20 total qubits (static per reference); target bit = 19 - qubit.
    const int shift = 19 - qubit[0];
    const unsigned int stride = 1u << shift;      // element stride (65536 for q=3)
    const unsigned int mask   = stride - 1u;

    float t = theta[0] * 0.5f;
    float s, c;
    sincosf(t, &s, &c);

    const unsigned int loff = lane * 4u;

    // Chunk lies inside one splice window iff stride >= 512 (qubit <= 10
    // at n=20; qubit=3 here), so after bit-insert it stays contiguous.
    unsigned int e0 = chunk * 512u + loff;
    unsigned int i0 = (e0 & mask) | ((e0 & ~mask) << 1);  // lower, sub A
    unsigned int j0 = i0 + 256u;                          // lower, sub B
    unsigned int i1 = i0 + stride;                        // upper, sub A
    unsigned int j1 = j0 + stride;                        // upper, sub B

    floatx4 a0 = *reinterpret_cast<const floatx4*>(in + i0);
    floatx4 a1 = *reinterpret_cast<const floatx4*>(in + j0);
    floatx4 b0 = *reinterpret_cast<const floatx4*>(in + i1);
    floatx4 b1 = *reinterpret_cast<const floatx4*>(in + j1);

    for (;;) {
        const unsigned int next = chunk + n_act_waves;
        const bool have_next = next < n_chunks;

        unsigned int ni0 = 0, nj0 = 0, ni1 = 0, nj1 = 0;
        floatx4 na0, na1, nb0, nb1;
        if (have_next) {
            unsigned int ne = next * 512u + loff;
            ni0 = (ne & mask) | ((ne & ~mask) << 1);
            nj0 = ni0 + 256u;
            ni1 = ni0 + stride;
            nj1 = nj0 + stride;
            na0 = *reinterpret_cast<const floatx4*>(in + ni0);
            na1 = *reinterpret_cast<const floatx4*>(in + nj0);
            nb0 = *reinterpret_cast<const floatx4*>(in + ni1);
            nb1 = *reinterpret_cast<const floatx4*>(in + nj1);
        }

        floatx4 y00 = c * a0 - s * b0;
        floatx4 y01 = c * a1 - s * b1;
        floatx4 y10 = s * a0 + c * b0;
        floatx4 y11 = s * a1 + c * b1;

        __builtin_nontemporal_store(y00, reinterpret_cast<floatx4*>(out + i0));
        __builtin_nontemporal_store(y01, reinterpret_cast<floatx4*>(out + j0));
        __builtin_nontemporal_store(y10, reinterpret_cast<floatx4*>(out + i1));
        __builtin_nontemporal_store(y11, reinterpret_cast<floatx4*>(out + j1));

        if (!have_next) break;
        chunk = next;
        i0 = ni0; j0 = nj0; i1 = ni1; j1 = nj1;
        a0 = na0; a1 = na1; b0 = nb0; b1 = nb1;
    }
}

// Scalar fallback (any qubit, incl. stride<512). Not used for qubit=3.
__global__ __launch_bounds__(256) void ry_gate_kernel_scalar(
    const float* __restrict__ in,
    const float* __restrict__ theta,
    const int*   __restrict__ qubit,
    float*       __restrict__ out,
    unsigned int n_pairs)
{
    unsigned int p = blockIdx.x * blockDim.x + threadIdx.x;
    if (p >= n_pairs) return;

    const int shift = 19 - qubit[0];
    const unsigned int stride = 1u << shift;
    const unsigned int mask   = stride - 1u;

    float t = theta[0] * 0.5f;
    float s, c;
    sincosf(t, &s, &c);

    unsigned int i0 = (p & mask) | ((p & ~mask) << 1);
    unsigned int i1 = i0 + stride;

    float x0 = in[i0], x1 = in[i1];
    out[i0] = c * x0 - s * x1;
    out[i1] = s * x0 + c * x1;
}

extern "C" void kernel_launch(void* const* d_in, const int* in_sizes, int n_in,
                              void* d_out, int out_size, void* d_ws, size_t ws_size,
                              hipStream_t stream)
{
    const float* state = (const float*)d_in[0];
    const float* theta = (const float*)d_in[1];
    const int*   qubit = (const int*)d_in[2];
    float*       out   = (float*)d_out;

    const unsigned int n_total  = (unsigned int)in_sizes[0];  // 32 * 2^20
    const unsigned int n_chunks = n_total / 1024u;            // 1024 elems/chunk
    const int block = 256;
    // Persistent-style: 2048 blocks = 8/CU, 8 waves/SIMD; each wave
    // grid-strides over n_chunks / 8192 = 4 chunks (for the 32*2^20 shape).
    unsigned int grid = (n_chunks * 64u + block - 1) / block;
    if (grid > 2048u) grid = 2048u;
    ry_gate_kernel<<<grid, block, 0, stream>>>(state, theta, qubit, out, n_chunks);
}

// Round 5
// 225.582 us; speedup vs baseline: 1.0414x; 1.0414x over previous
//
#include <hip/hip_runtime.h>

// RY(theta) single-qubit gate on batched state vector.
// state: [B=32, 2^20] fp32. Target qubit q (static=3) maps to flat-index
// bit (20-1-q) = 16, i.e. element stride 2^16. Butterfly per pair:
//   y0 = c*x0 - s*x1 ; y1 = s*x0 + c*x1 ; t=theta/2, c=cos t, s=sin t.
// Memory-bound: 256 MiB app traffic -> ~43 us floor at 6.3 TB/s.
//
// R7: wave pairing via LDS -> per-wave copy-shaped traffic.
// Evidence so far: traffic ideal (R4: FETCH 64Mi w/ LLC hits, WRITE 128Mi
// exact), hints best at all-NT (R3=225 vs PP=232 vs PN=235), structure
// flat (one-shot == persistent+pipelined), fill saturates at 9% occupancy
// so TLP/MLP exonerated. Remaining mechanical difference vs the 6.29 TB/s
// copy ubench: streams per wave (fill=1 -> 6.7, copy=2 -> 6.29, ours=4 ->
// ~4.1 TB/s; read pair 256 KiB apart). This round: block = 4 waves; waves
// 0-1 load ONLY the lower segment, waves 2-3 ONLY the upper; halves are
// exchanged through double-buffered LDS (conflict-free b128: 16 lanes x
// 16 B = all 32 banks once); each wave stores only its own segment at the
// SAME addresses it read. Per wave: 1 dense read stream + 1 dense write
// stream. One barrier per tile; next-tile loads issued pre-barrier so
// stores(t) overlap loads(t+1). All-NT hints kept (known best).

typedef float floatx4 __attribute__((ext_vector_type(4)));

__global__ __launch_bounds__(256) void ry_gate_kernel(
    const float* __restrict__ in,
    const float* __restrict__ theta,
    const int*   __restrict__ qubit,
    float*       __restrict__ out,
    unsigned int n_tiles)   // tiles of 1024 lower + 1024 upper floats
{
    // [buf][side][elem]: 2 x 2 x 1024 floats = 16 KiB (8 blocks/CU -> 128 KiB)
    __shared__ float lds[2][2][1024];

    const unsigned int tid  = threadIdx.x;        // 0..255
    const unsigned int side = tid >> 7;           // 0 = lower half, 1 = upper
    const unsigned int tt   = tid & 127u;         // lane-slot within side
    const unsigned int nblk = gridDim.x;

    // n = 20 total qubits (static per reference); target bit = 19 - qubit.
    const int shift = 19 - qubit[0];
    const unsigned int stride = 1u << shift;      // 65536 for q=3
    const unsigned int mask   = stride - 1u;

    float t = theta[0] * 0.5f;
    float s, c;
    sincosf(t, &s, &c);

    unsigned int tile = blockIdx.x;
    if (tile >= n_tiles) return;                  // uniform per block

    // Tile = 1024 consecutive lower-half elements (+ partners). Contiguity
    // after bit-insert requires stride >= 1024 (qubit <= 9 at n=20; q=3 ok).
    const unsigned int toff = side * stride + tt * 4u;
    auto baseof = [&](unsigned int tl) -> unsigned int {
        unsigned int e = tl * 1024u;
        return ((e & mask) | ((e & ~mask) << 1)) + toff;
    };

    unsigned int base = baseof(tile);
    floatx4 own0 = __builtin_nontemporal_load(reinterpret_cast<const floatx4*>(in + base));
    floatx4 own1 = __builtin_nontemporal_load(reinterpret_cast<const floatx4*>(in + base + 512u));

    unsigned int buf = 0;
    for (;;) {
        const unsigned int next = tile + nblk;
        const bool have_next = next < n_tiles;    // uniform per block

        // Stage own segment into LDS (dense b128, conflict-free).
        *reinterpret_cast<floatx4*>(&lds[buf][side][tt * 4u])        = own0;
        *reinterpret_cast<floatx4*>(&lds[buf][side][tt * 4u + 512u]) = own1;

        // Issue next tile's global loads before the barrier (overlap).
        unsigned int nbase = 0;
        floatx4 nown0, nown1;
        if (have_next) {
            nbase = baseof(next);
            nown0 = __builtin_nontemporal_load(reinterpret_cast<const floatx4*>(in + nbase));
            nown1 = __builtin_nontemporal_load(reinterpret_cast<const floatx4*>(in + nbase + 512u));
        }

        __syncthreads();

        // Read partner half from LDS; compute own outputs; store to the
        // same addresses this wave loaded from (1 write stream).
        floatx4 par0 = *reinterpret_cast<const floatx4*>(&lds[buf][side ^ 1u][tt * 4u]);
        floatx4 par1 = *reinterpret_cast<const floatx4*>(&lds[buf][side ^ 1u][tt * 4u + 512u]);

        floatx4 y0, y1;
        if (side == 0) {            // own = x0, partner = x1
            y0 = c * own0 - s * par0;
            y1 = c * own1 - s * par1;
        } else {                    // own = x1, partner = x0
            y0 = s * par0 + c * own0;
            y1 = s * par1 + c * own1;
        }
        __builtin_nontemporal_store(y0, reinterpret_cast<floatx4*>(out + base));
        __builtin_nontemporal_store(y1, reinterpret_cast<floatx4*>(out + base + 512u));

        if (!have_next) break;
        tile = next; base = nbase;
        own0 = nown0; own1 = nown1;
        buf ^= 1;
        // Safety: buf's previous readers finished before the barrier above;
        // re-write of this buf happens 2 iterations later, past >=1 barrier.
    }
}

// Scalar fallback (any qubit, incl. stride<1024). Not used for qubit=3.
__global__ __launch_bounds__(256) void ry_gate_kernel_scalar(
    const float* __restrict__ in,
    const float* __restrict__ theta,
    const int*   __restrict__ qubit,
    float*       __restrict__ out,
    unsigned int n_pairs)
{
    unsigned int p = blockIdx.x * blockDim.x + threadIdx.x;
    if (p >= n_pairs) return;

    const int shift = 19 - qubit[0];
    const unsigned int stride = 1u << shift;
    const unsigned int mask   = stride - 1u;

    float t = theta[0] * 0.5f;
    float s, c;
    sincosf(t, &s, &c);

    unsigned int i0 = (p & mask) | ((p & ~mask) << 1);
    unsigned int i1 = i0 + stride;

    float x0 = in[i0], x1 = in[i1];
    out[i0] = c * x0 - s * x1;
    out[i1] = s * x0 + c * x1;
}

extern "C" void kernel_launch(void* const* d_in, const int* in_sizes, int n_in,
                              void* d_out, int out_size, void* d_ws, size_t ws_size,
                              hipStream_t stream)
{
    const float* state = (const float*)d_in[0];
    const float* theta = (const float*)d_in[1];
    const int*   qubit = (const int*)d_in[2];
    float*       out   = (float*)d_out;

    const unsigned int n_total = (unsigned int)in_sizes[0];   // 32 * 2^20
    const unsigned int n_tiles = n_total / 2048u;             // 1024 pairs/tile
    const int block = 256;
    unsigned int grid = n_tiles < 2048u ? n_tiles : 2048u;    // 8 blocks/CU
    ry_gate_kernel<<<grid, block, 0, stream>>>(state, theta, qubit, out, n_tiles);
}